// Round 8
// baseline (248.391 us; speedup 1.0000x reference)
//
#include <hip/hip_runtime.h>
#include <hip/hip_bf16.h>
#include <math.h>

#define HID 128
#define NRAD 6
#define TABN 2048          // nearest-neighbor table rows 0..TABN (row TABN = 0, x>=1 gate)
#define CUTOFF_INV 0.2f
#define MZ 95
#define PAD 16             // padded-CSR slots per node (one 64B segment); overflow -> spill list
#define OVF_CAP 65536

typedef unsigned int uint32;

// ---------- K1 (fused): bf16 T1(+b_lin)/T2 + ftab + edge pass (count + padded scatter) ----------
__global__ void build1(const float* __restrict__ emb, const float* __restrict__ W_lin,
                       const float* __restrict__ freq, const float* __restrict__ W_rbf,
                       const float* __restrict__ b_rbf, const float* __restrict__ b_lin,
                       const int* __restrict__ ei, const float* __restrict__ pos,
                       const int* __restrict__ z,
                       __hip_bfloat16* __restrict__ Tb, float* __restrict__ ftab,
                       int* __restrict__ cnt, int* __restrict__ payload,
                       int* __restrict__ ovfcnt, int2* __restrict__ ovfbuf,
                       int MAXZ, int E) {
    __shared__ float sh[HID];
    int h   = threadIdx.x;
    int bid = blockIdx.x;
    int nT  = 2 * MAXZ;
    int nF  = TABN + 1;
    if (bid < nT) {
        int zz = bid >> 1, s = bid & 1;
        sh[h] = emb[zz * HID + h];
        __syncthreads();
        const float* W = W_lin + (size_t)s * HID * HID;
        float acc = (s == 0) ? b_lin[h] : 0.f;   // fold bias into T1
#pragma unroll 8
        for (int k = 0; k < HID; ++k) acc = fmaf(sh[k], W[k * HID + h], acc);
        Tb[(size_t)(s * MAXZ + zz) * HID + h] = __float2bfloat16(acc);
    } else if (bid < nT + nF) {
        int t = bid - nT;   // 0..TABN
        float rbf[NRAD];
        if (t == 0) {
#pragma unroll
            for (int k = 0; k < NRAD; ++k) rbf[k] = freq[k];   // lim x->0 env*sin(fx)=f
        } else if (t >= TABN) {
#pragma unroll
            for (int k = 0; k < NRAD; ++k) rbf[k] = 0.f;       // envelope gate x>=1
        } else {
            float x  = (float)t / (float)TABN;
            float x2 = x * x, x5 = x2 * x2 * x;
            float env = 1.f / x + x5 * (-28.f + x * (48.f + x * (-21.f)));
#pragma unroll
            for (int k = 0; k < NRAD; ++k) rbf[k] = env * sinf(freq[k] * x);
        }
        float pre = b_rbf[h];
#pragma unroll
        for (int k = 0; k < NRAD; ++k) pre = fmaf(rbf[k], W_rbf[k * HID + h], pre);
        sh[h] = pre / (1.f + __expf(-pre));   // precise silu (once per table row)
        __syncthreads();
        const float* W3 = W_lin + (size_t)2 * HID * HID;
        float acc = 0.f;
#pragma unroll 8
        for (int k = 0; k < HID; ++k) acc = fmaf(sh[k], W3[k * HID + h], acc);
        ftab[(size_t)t * HID + h] = acc;
    } else {
        // edge pass: distance -> table index, rank via one atomic, direct padded write
        int e = (bid - nT - nF) * HID + h;
        if (e < E) {
            int i = ei[e];
            int j = ei[E + e];
            float dx = pos[3 * i]     - pos[3 * j];
            float dy = pos[3 * i + 1] - pos[3 * j + 1];
            float dz = pos[3 * i + 2] - pos[3 * j + 2];
            float d  = sqrtf(dx * dx + dy * dy + dz * dz);
            float u  = fminf(d * CUTOFF_INV, 1.0f) * (float)TABN;
            int   ti = (int)(u + 0.5f);          // nearest
            if (ti > TABN) ti = TABN;
            int pl = ti | (z[i] << 13) | (z[j] << 20);
            int r  = atomicAdd(&cnt[j], 1);
            if (r < PAD) {
                payload[j * PAD + r] = pl;
            } else {
                int o = atomicAdd(ovfcnt, 1);
                if (o < OVF_CAP) ovfbuf[o] = make_int2(j, pl);
            }
        }
    }
}

// ---------- gather: 32 lanes/edge, float4 columns, paired edges for ILP ----------
__launch_bounds__(1024)
__global__ void gather_k(const int* __restrict__ cnt, const int* __restrict__ payload,
                         const uint32* __restrict__ Tb32, const float* __restrict__ ftab,
                         const int* __restrict__ ovfcnt, const int2* __restrict__ ovfbuf,
                         float* __restrict__ out, int N) {
    __shared__ uint32 sT[2 * MZ * (HID / 2)];    // 48640 B, bf16 pairs
    int tid = threadIdx.x;
    for (int k = tid; k < 2 * MZ * (HID / 2); k += 1024) sT[k] = Tb32[k];
    __syncthreads();

    int lane = tid & 31, grp = tid >> 5;         // 32 node-groups/block, 32 lanes/node
    int h4   = lane * 4;
    const uint32* sT2 = sT + MZ * (HID / 2);
    const float*  ft  = ftab + h4;
    int nCh = (N + 31) >> 5;

    for (int ch = blockIdx.x; ch < nCh; ch += gridDim.x) {
        int n = (ch << 5) + grp;
        if (n >= N) continue;
        int deg = cnt[n];                                   // true degree (may exceed PAD)
        int cb  = deg < PAD ? deg : PAD;
        int plv = payload[n * PAD + (lane & (PAD - 1))];    // one 64B segment, coalesced

        float e0 = 0.f, e1 = 0.f, e2 = 0.f, e3 = 0.f;       // even-edge accumulator
        float o0 = 0.f, o1 = 0.f, o2 = 0.f, o3 = 0.f;       // odd-edge accumulator
        auto edge = [&](int pl, float& b0, float& b1, float& b2, float& b3) {
            int ti = pl & 0x1FFF;
            int zi = (pl >> 13) & 0x7F;
            int zj = (pl >> 20) & 0x7F;
            float4 f  = *(const float4*)(ft + (size_t)ti * HID);
            uint2  u1 = *(const uint2*)(sT  + zi * (HID / 2) + lane * 2);
            uint2  u2 = *(const uint2*)(sT2 + zj * (HID / 2) + lane * 2);
            float p0 = __uint_as_float(u1.x << 16)         + __uint_as_float(u2.x << 16)         + f.x;
            float p1 = __uint_as_float(u1.x & 0xFFFF0000u) + __uint_as_float(u2.x & 0xFFFF0000u) + f.y;
            float p2 = __uint_as_float(u1.y << 16)         + __uint_as_float(u2.y << 16)         + f.z;
            float p3 = __uint_as_float(u1.y & 0xFFFF0000u) + __uint_as_float(u2.y & 0xFFFF0000u) + f.w;
            b0 = fmaf(p0, __builtin_amdgcn_rcpf(1.f + __expf(-p0)), b0);
            b1 = fmaf(p1, __builtin_amdgcn_rcpf(1.f + __expf(-p1)), b1);
            b2 = fmaf(p2, __builtin_amdgcn_rcpf(1.f + __expf(-p2)), b2);
            b3 = fmaf(p3, __builtin_amdgcn_rcpf(1.f + __expf(-p3)), b3);
        };
        int k = 0;
        for (; k + 2 <= cb; k += 2) {                       // paired: 2 indep chains in flight
            int plA = __shfl(plv, k, 32);
            int plB = __shfl(plv, k + 1, 32);
            edge(plA, e0, e1, e2, e3);
            edge(plB, o0, o1, o2, o3);
        }
        if (k < cb) { int plA = __shfl(plv, k, 32); edge(plA, e0, e1, e2, e3); }

        if (deg > PAD) {                                    // rare spill path (in-wave fixup)
            int nov = *ovfcnt;
            if (nov > OVF_CAP) nov = OVF_CAP;
            for (int o = 0; o < nov; ++o) {
                int2 v = ovfbuf[o];
                if (v.x == n) edge(v.y, e0, e1, e2, e3);
            }
        }
        float s = (deg > 0) ? 1.0f / (float)deg : 0.0f;
        float4 v;
        v.x = (e0 + o0) * s; v.y = (e1 + o1) * s;
        v.z = (e2 + o2) * s; v.w = (e3 + o3) * s;
        *(float4*)(out + (size_t)n * HID + h4) = v;
    }
}

// ---------- launch ----------
extern "C" void kernel_launch(void* const* d_in, const int* in_sizes, int n_in,
                              void* d_out, int out_size, void* d_ws, size_t ws_size,
                              hipStream_t stream) {
    const int*   z     = (const int*)d_in[0];
    const float* pos   = (const float*)d_in[1];
    const int*   ei    = (const int*)d_in[2];
    const float* freq  = (const float*)d_in[3];
    const float* emb   = (const float*)d_in[4];
    const float* W_rbf = (const float*)d_in[5];
    const float* b_rbf = (const float*)d_in[6];
    const float* W_lin = (const float*)d_in[7];
    const float* b_lin = (const float*)d_in[8];

    int N    = in_sizes[0];
    int E    = in_sizes[2] / 2;
    int MAXZ = in_sizes[4] / HID;   // 95 == MZ
    float* out = (float*)d_out;

    int N_pad = ((N + 1024) / 1024) * 1024;   // multiple of 1024, strictly > N

    char* ws = (char*)d_ws;
    size_t off = 0;
    auto alloc = [&](size_t bytes) { char* p = ws + off; off = (off + bytes + 255) & ~(size_t)255; return p; };
    int*   cnt     = (int*)alloc((size_t)N_pad * 4);     // N_pad*4 is 256-aligned
    int*   ovfcnt  = (int*)alloc(256);                   // adjacent to cnt for one memset
    __hip_bfloat16* Tb = (__hip_bfloat16*)alloc((size_t)2 * MAXZ * HID * 2);
    float* ftab    = (float*)alloc((size_t)(TABN + 1) * HID * 4);
    int*   payload = (int*)alloc((size_t)N_pad * PAD * 4);
    int2*  ovfbuf  = (int2*)alloc((size_t)OVF_CAP * 8);

    hipMemsetAsync(cnt, 0, (size_t)N_pad * 4 + 256, stream);   // zeros cnt + ovfcnt

    int nBuild = 2 * MAXZ + (TABN + 1) + (E + HID - 1) / HID;
    build1<<<nBuild, HID, 0, stream>>>(emb, W_lin, freq, W_rbf, b_rbf, b_lin,
                                       ei, pos, z, Tb, ftab, cnt, payload,
                                       ovfcnt, ovfbuf, MAXZ, E);
    gather_k<<<512, 1024, 0, stream>>>(cnt, payload, (const uint32*)Tb, ftab,
                                       ovfcnt, ovfbuf, out, N);
}